// Round 1
// baseline (707.117 us; speedup 1.0000x reference)
//
#include <hip/hip_runtime.h>

// GraphSAGE 2-layer (mean agg), N=100K nodes, E=1.6M edges, 128->128->64, f32.
// Strategy: build CSR-by-dst in-launch (deg -> scan -> fill), gather-aggregate
// (no float atomics), then f32 tiled GEMM for [h|agg] @ [Wself;Wneigh] + b, relu.

__global__ __launch_bounds__(256) void k_degree(const int* __restrict__ dst,
                                                int* __restrict__ deg, int E) {
  int e = blockIdx.x * 256 + threadIdx.x;
  if (e < E) atomicAdd(&deg[dst[e]], 1);
}

__global__ __launch_bounds__(256) void k_scan_reduce(const int* __restrict__ deg,
                                                     int* __restrict__ bsum, int n) {
  __shared__ int s[256];
  int i = blockIdx.x * 256 + threadIdx.x;
  s[threadIdx.x] = (i < n) ? deg[i] : 0;
  __syncthreads();
  for (int off = 128; off > 0; off >>= 1) {
    if (threadIdx.x < off) s[threadIdx.x] += s[threadIdx.x + off];
    __syncthreads();
  }
  if (threadIdx.x == 0) bsum[blockIdx.x] = s[0];
}

__global__ __launch_bounds__(512) void k_scan_blocksums(const int* __restrict__ bsum,
                                                        int* __restrict__ boff, int nb) {
  __shared__ int s[512];
  int t = threadIdx.x;
  int v = (t < nb) ? bsum[t] : 0;
  s[t] = v;
  __syncthreads();
  for (int off = 1; off < 512; off <<= 1) {
    int x = (t >= off) ? s[t - off] : 0;
    __syncthreads();
    s[t] += x;
    __syncthreads();
  }
  if (t < nb) boff[t] = s[t] - v;  // exclusive
}

__global__ __launch_bounds__(256) void k_scan_final(const int* __restrict__ deg,
                                                    const int* __restrict__ boff,
                                                    int* __restrict__ rs,
                                                    int* __restrict__ cur, int n) {
  __shared__ int s[256];
  int t = threadIdx.x;
  int i = blockIdx.x * 256 + t;
  int v = (i < n) ? deg[i] : 0;
  s[t] = v;
  __syncthreads();
  for (int off = 1; off < 256; off <<= 1) {
    int x = (t >= off) ? s[t - off] : 0;
    __syncthreads();
    s[t] += x;
    __syncthreads();
  }
  if (i < n) {
    int ex = boff[blockIdx.x] + s[t] - v;
    rs[i] = ex;
    cur[i] = ex;
  }
}

__global__ __launch_bounds__(256) void k_fill(const int* __restrict__ src,
                                              const int* __restrict__ dst,
                                              int* __restrict__ cur,
                                              int* __restrict__ col, int E) {
  int e = blockIdx.x * 256 + threadIdx.x;
  if (e < E) {
    int pos = atomicAdd(&cur[dst[e]], 1);
    col[pos] = src[e];
  }
}

// Mean-aggregate: one 64-lane wave per node, lane covers 2 of 128 feats (float2).
__global__ __launch_bounds__(256) void k_agg(const float* __restrict__ X,
                                             const int* __restrict__ col,
                                             const int* __restrict__ rs,
                                             const int* __restrict__ deg,
                                             float* __restrict__ out, int n) {
  int node = blockIdx.x * 4 + (threadIdx.x >> 6);
  if (node >= n) return;
  int lane = threadIdx.x & 63;
  int r0 = rs[node];
  int d = deg[node];
  float2 s = make_float2(0.f, 0.f);
  for (int j = 0; j < d; j++) {
    int c = __builtin_amdgcn_readfirstlane(col[r0 + j]);
    float2 v = *reinterpret_cast<const float2*>(&X[(size_t)c * 128 + lane * 2]);
    s.x += v.x;
    s.y += v.y;
  }
  float rinv = 1.0f / fmaxf((float)d, 1.0f);
  s.x *= rinv;
  s.y *= rinv;
  *reinterpret_cast<float2*>(&out[(size_t)node * 128 + lane * 2]) = s;
}

// out[m][j] = relu( sum_k A[m][k]*W1[k][j] + G[m][k]*W2[k][j] + bias[j] )
// Virtual GEMM: M x 256 x BN. Tile BM=128, BK=16, 256 threads, thread tile 8xTN.
template <int BN, int TN>
__global__ __launch_bounds__(256) void k_combine(const float* __restrict__ A,
                                                 const float* __restrict__ G,
                                                 const float* __restrict__ W1,
                                                 const float* __restrict__ W2,
                                                 const float* __restrict__ bias,
                                                 float* __restrict__ Out, int M) {
  constexpr int BM = 128, BK = 16;
  __shared__ float Xs[BK][BM + 4];
  __shared__ float Ws[BK][BN + 4];
  const int m0 = blockIdx.x * BM;
  const int t = threadIdx.x;
  const int tx = t & 15, ty = t >> 4;
  float acc[8][TN] = {};

  for (int kk = 0; kk < 256; kk += BK) {
    // stage X tile (transposed to Xs[k][m]); 128x16 = 512 float4s, 2 per thread
#pragma unroll
    for (int i = 0; i < 2; i++) {
      int idx = t + i * 256;
      int m = idx >> 2;
      int k4 = (idx & 3) << 2;
      int gm = m0 + m;
      int gk = kk + k4;
      float4 v = make_float4(0.f, 0.f, 0.f, 0.f);
      if (gm < M) {
        const float* p = (gk < 128) ? (A + (size_t)gm * 128 + gk)
                                    : (G + (size_t)gm * 128 + (gk - 128));
        v = *reinterpret_cast<const float4*>(p);
      }
      Xs[k4 + 0][m] = v.x;
      Xs[k4 + 1][m] = v.y;
      Xs[k4 + 2][m] = v.z;
      Xs[k4 + 3][m] = v.w;
    }
    // stage W tile Ws[k][j]
    constexpr int WITER = (BK * BN / 4) / 256;
#pragma unroll
    for (int i = 0; i < WITER; i++) {
      int idx = t + i * 256;
      int k = idx / (BN / 4);
      int j4 = (idx % (BN / 4)) << 2;
      int gk = kk + k;
      const float* p = (gk < 128) ? (W1 + (size_t)gk * BN + j4)
                                  : (W2 + (size_t)(gk - 128) * BN + j4);
      *reinterpret_cast<float4*>(&Ws[k][j4]) = *reinterpret_cast<const float4*>(p);
    }
    __syncthreads();
#pragma unroll
    for (int k = 0; k < BK; k++) {
      float4 a0 = *reinterpret_cast<const float4*>(&Xs[k][ty * 8]);
      float4 a1 = *reinterpret_cast<const float4*>(&Xs[k][ty * 8 + 4]);
      float av[8] = {a0.x, a0.y, a0.z, a0.w, a1.x, a1.y, a1.z, a1.w};
      float bv[TN];
      if constexpr (TN == 8) {
        float4 b0 = *reinterpret_cast<const float4*>(&Ws[k][tx * 8]);
        float4 b1 = *reinterpret_cast<const float4*>(&Ws[k][tx * 8 + 4]);
        bv[0] = b0.x; bv[1] = b0.y; bv[2] = b0.z; bv[3] = b0.w;
        bv[4] = b1.x; bv[5] = b1.y; bv[6] = b1.z; bv[7] = b1.w;
      } else {
        float4 b0 = *reinterpret_cast<const float4*>(&Ws[k][tx * 4]);
        bv[0] = b0.x; bv[1] = b0.y; bv[2] = b0.z; bv[3] = b0.w;
      }
#pragma unroll
      for (int i = 0; i < 8; i++)
#pragma unroll
        for (int j = 0; j < TN; j++) acc[i][j] = fmaf(av[i], bv[j], acc[i][j]);
    }
    __syncthreads();
  }

  float bb[TN];
#pragma unroll
  for (int j = 0; j < TN; j++) bb[j] = bias[tx * TN + j];
#pragma unroll
  for (int i = 0; i < 8; i++) {
    int gm = m0 + ty * 8 + i;
    if (gm >= M) continue;
    float* op = Out + (size_t)gm * BN + tx * TN;
#pragma unroll
    for (int j0 = 0; j0 < TN; j0 += 4) {
      float4 o;
      o.x = fmaxf(acc[i][j0 + 0] + bb[j0 + 0], 0.f);
      o.y = fmaxf(acc[i][j0 + 1] + bb[j0 + 1], 0.f);
      o.z = fmaxf(acc[i][j0 + 2] + bb[j0 + 2], 0.f);
      o.w = fmaxf(acc[i][j0 + 3] + bb[j0 + 3], 0.f);
      *reinterpret_cast<float4*>(op + j0) = o;
    }
  }
}

extern "C" void kernel_launch(void* const* d_in, const int* in_sizes, int n_in,
                              void* d_out, int out_size, void* d_ws, size_t ws_size,
                              hipStream_t stream) {
  const float* h = (const float*)d_in[0];
  const int* esrc = (const int*)d_in[1];
  const int* edst = (const int*)d_in[2];
  const float* Ws1 = (const float*)d_in[3];
  const float* Wn1 = (const float*)d_in[4];
  const float* b1 = (const float*)d_in[5];
  const float* Ws2 = (const float*)d_in[6];
  const float* Wn2 = (const float*)d_in[7];
  const float* b2 = (const float*)d_in[8];
  float* out = (float*)d_out;

  const int N = in_sizes[0] / 128;  // 100000
  const int E = in_sizes[1];        // 1600000

  char* base = (char*)d_ws;
  size_t off = 0;
  auto alloc = [&](size_t bytes) {
    size_t o = off;
    off += (bytes + 255) & ~(size_t)255;
    return o;
  };
  int* deg = (int*)(base + alloc((size_t)N * 4));
  int* rs = (int*)(base + alloc((size_t)N * 4));
  int* cur = (int*)(base + alloc((size_t)N * 4));
  int* bsum = (int*)(base + alloc(512 * 4));
  int* boff = (int*)(base + alloc(512 * 4));
  int* col = (int*)(base + alloc((size_t)E * 4));
  float* agg = (float*)(base + alloc((size_t)N * 128 * 4));
  float* h1 = (float*)(base + alloc((size_t)N * 128 * 4));

  const int NB1 = (N + 255) / 256;  // 391 (<= 512 for single-block scan)

  hipMemsetAsync(deg, 0, (size_t)N * 4, stream);
  k_degree<<<(E + 255) / 256, 256, 0, stream>>>(edst, deg, E);
  k_scan_reduce<<<NB1, 256, 0, stream>>>(deg, bsum, N);
  k_scan_blocksums<<<1, 512, 0, stream>>>(bsum, boff, NB1);
  k_scan_final<<<NB1, 256, 0, stream>>>(deg, boff, rs, cur, N);
  k_fill<<<(E + 255) / 256, 256, 0, stream>>>(esrc, edst, cur, col, E);

  // Layer 1: agg(h) -> combine -> h1 (relu)
  k_agg<<<(N + 3) / 4, 256, 0, stream>>>(h, col, rs, deg, agg, N);
  k_combine<128, 8><<<(N + 127) / 128, 256, 0, stream>>>(h, agg, Ws1, Wn1, b1, h1, N);

  // Layer 2: agg(h1) -> combine -> out (relu)
  k_agg<<<(N + 3) / 4, 256, 0, stream>>>(h1, col, rs, deg, agg, N);
  k_combine<64, 4><<<(N + 127) / 128, 256, 0, stream>>>(h1, agg, Ws2, Wn2, b2, out, N);
}

// Round 3
// 386.862 us; speedup vs baseline: 1.8278x; 1.8278x over previous
//
#include <hip/hip_runtime.h>

// GraphSAGE 2-layer (mean agg), N=100K, E=1.6M, 128->128->64, f32 in/out.
// bf16 features + MFMA GEMM. CSR-by-dst built in-launch (deg->scan->fill),
// gather-aggregate (no float atomics), combine = [h|agg] @ [Wself;Wneigh] + b, relu.
// bf16 carried as raw ushort (this ROCm's __hip_bfloat16 lacks .data).

typedef __attribute__((ext_vector_type(8))) short short8;
typedef __attribute__((ext_vector_type(4))) float f32x4;

__device__ __forceinline__ ushort f2bf(float f) {
  uint u = __float_as_uint(f);
  u += 0x7fffu + ((u >> 16) & 1u);  // round-to-nearest-even
  return (ushort)(u >> 16);
}

#define GLDS(src, dst)                                                        \
  __builtin_amdgcn_global_load_lds(                                           \
      (const __attribute__((address_space(1))) void*)(src),                   \
      (__attribute__((address_space(3))) void*)(dst), 16, 0, 0)

// ---------------- CSR build ----------------
__global__ __launch_bounds__(256) void k_degree(const int* __restrict__ dst,
                                                int* __restrict__ deg, int E) {
  int e = blockIdx.x * 256 + threadIdx.x;
  if (e < E) atomicAdd(&deg[dst[e]], 1);
}

__global__ __launch_bounds__(256) void k_scan_reduce(const int* __restrict__ deg,
                                                     int* __restrict__ bsum, int n) {
  __shared__ int s[256];
  int i = blockIdx.x * 256 + threadIdx.x;
  s[threadIdx.x] = (i < n) ? deg[i] : 0;
  __syncthreads();
  for (int off = 128; off > 0; off >>= 1) {
    if (threadIdx.x < off) s[threadIdx.x] += s[threadIdx.x + off];
    __syncthreads();
  }
  if (threadIdx.x == 0) bsum[blockIdx.x] = s[0];
}

__global__ __launch_bounds__(512) void k_scan_blocksums(const int* __restrict__ bsum,
                                                        int* __restrict__ boff, int nb) {
  __shared__ int s[512];
  int t = threadIdx.x;
  int v = (t < nb) ? bsum[t] : 0;
  s[t] = v;
  __syncthreads();
  for (int off = 1; off < 512; off <<= 1) {
    int x = (t >= off) ? s[t - off] : 0;
    __syncthreads();
    s[t] += x;
    __syncthreads();
  }
  if (t < nb) boff[t] = s[t] - v;  // exclusive
}

__global__ __launch_bounds__(256) void k_scan_final(const int* __restrict__ deg,
                                                    const int* __restrict__ boff,
                                                    int* __restrict__ rs,
                                                    int* __restrict__ cur, int n) {
  __shared__ int s[256];
  int t = threadIdx.x;
  int i = blockIdx.x * 256 + t;
  int v = (i < n) ? deg[i] : 0;
  s[t] = v;
  __syncthreads();
  for (int off = 1; off < 256; off <<= 1) {
    int x = (t >= off) ? s[t - off] : 0;
    __syncthreads();
    s[t] += x;
    __syncthreads();
  }
  if (i < n) {
    int ex = boff[blockIdx.x] + s[t] - v;
    rs[i] = ex;
    cur[i] = ex;
  }
}

__global__ __launch_bounds__(256) void k_fill(const int* __restrict__ src,
                                              const int* __restrict__ dst,
                                              int* __restrict__ cur,
                                              int* __restrict__ col, int E) {
  int e = blockIdx.x * 256 + threadIdx.x;
  if (e < E) {
    int pos = atomicAdd(&cur[dst[e]], 1);
    col[pos] = src[e];
  }
}

// ---------------- prep: f32 -> bf16 cast of h ----------------
__global__ __launch_bounds__(256) void k_cast(const float* __restrict__ in,
                                              ushort* __restrict__ out, int n8) {
  int i = blockIdx.x * 256 + threadIdx.x;
  if (i >= n8) return;
  const float4* p = reinterpret_cast<const float4*>(in) + i * 2;
  float4 a = p[0], b = p[1];
  ushort u[8];
  u[0] = f2bf(a.x); u[1] = f2bf(a.y); u[2] = f2bf(a.z); u[3] = f2bf(a.w);
  u[4] = f2bf(b.x); u[5] = f2bf(b.y); u[6] = f2bf(b.z); u[7] = f2bf(b.w);
  *reinterpret_cast<ulonglong2*>(out + (size_t)i * 8) =
      *reinterpret_cast<ulonglong2*>(u);
}

// ---------------- prep: transpose+concat weights to bf16 Wt[n][256] ----------
__global__ __launch_bounds__(256) void k_prep_w(const float* __restrict__ Ws1,
                                                const float* __restrict__ Wn1,
                                                const float* __restrict__ Ws2,
                                                const float* __restrict__ Wn2,
                                                ushort* __restrict__ Wt1,
                                                ushort* __restrict__ Wt2) {
  int idx = blockIdx.x * 256 + threadIdx.x;
  if (idx < 128 * 256) {
    int n = idx >> 8, k = idx & 255;
    float v = (k < 128) ? Ws1[(size_t)k * 128 + n] : Wn1[(size_t)(k - 128) * 128 + n];
    Wt1[idx] = f2bf(v);
  } else if (idx < 128 * 256 + 64 * 256) {
    int j = idx - 128 * 256;
    int n = j >> 8, k = j & 255;
    float v = (k < 128) ? Ws2[(size_t)k * 64 + n] : Wn2[(size_t)(k - 128) * 64 + n];
    Wt2[j] = f2bf(v);
  }
}

// ---------------- mean-aggregate (bf16 rows, 256B each) ----------------
// one 64-lane wave per node; lane covers feats [2*lane, 2*lane+1] (one dword).
__global__ __launch_bounds__(256) void k_agg_b(const ushort* __restrict__ Xb,
                                               const int* __restrict__ col,
                                               const int* __restrict__ rs,
                                               const int* __restrict__ deg,
                                               ushort* __restrict__ outb, int n) {
  int node = blockIdx.x * 4 + (threadIdx.x >> 6);
  if (node >= n) return;
  int lane = threadIdx.x & 63;
  int r0 = rs[node];
  int d = deg[node];
  float ax0 = 0.f, ay0 = 0.f, ax1 = 0.f, ay1 = 0.f;
  float ax2 = 0.f, ay2 = 0.f, ax3 = 0.f, ay3 = 0.f;
  int j = 0;
  while (j < d) {
    int cnt = min(d - j, 64);
    int myc = (lane < cnt) ? col[r0 + j + lane] : 0;
    int jj = 0;
    for (; jj + 4 <= cnt; jj += 4) {
      int c0 = __shfl(myc, jj, 64);
      int c1 = __shfl(myc, jj + 1, 64);
      int c2 = __shfl(myc, jj + 2, 64);
      int c3 = __shfl(myc, jj + 3, 64);
      uint v0 = *reinterpret_cast<const uint*>(&Xb[(size_t)c0 * 128 + lane * 2]);
      uint v1 = *reinterpret_cast<const uint*>(&Xb[(size_t)c1 * 128 + lane * 2]);
      uint v2 = *reinterpret_cast<const uint*>(&Xb[(size_t)c2 * 128 + lane * 2]);
      uint v3 = *reinterpret_cast<const uint*>(&Xb[(size_t)c3 * 128 + lane * 2]);
      ax0 += __uint_as_float(v0 << 16); ay0 += __uint_as_float(v0 & 0xffff0000u);
      ax1 += __uint_as_float(v1 << 16); ay1 += __uint_as_float(v1 & 0xffff0000u);
      ax2 += __uint_as_float(v2 << 16); ay2 += __uint_as_float(v2 & 0xffff0000u);
      ax3 += __uint_as_float(v3 << 16); ay3 += __uint_as_float(v3 & 0xffff0000u);
    }
    for (; jj < cnt; jj++) {
      int c0 = __shfl(myc, jj, 64);
      uint v0 = *reinterpret_cast<const uint*>(&Xb[(size_t)c0 * 128 + lane * 2]);
      ax0 += __uint_as_float(v0 << 16); ay0 += __uint_as_float(v0 & 0xffff0000u);
    }
    j += cnt;
  }
  float rinv = 1.0f / fmaxf((float)d, 1.0f);
  float sx = (ax0 + ax1 + ax2 + ax3) * rinv;
  float sy = (ay0 + ay1 + ay2 + ay3) * rinv;
  ushort2 o;
  o.x = f2bf(sx);
  o.y = f2bf(sy);
  *reinterpret_cast<ushort2*>(&outb[(size_t)node * 128 + lane * 2]) = o;
}

// ---------------- combine: relu( [Xb|Gb] @ Wt^T + bias ) via MFMA ----------
// Wt layout: [BN][256] bf16 (pre-transposed, k 0..127 = W_self, 128..255 = W_neigh).
// Block: 256 thr = 4 waves (2x2), BM=128, wave tile 64 x (BN/2).
// LDS tiles per K-chunk of 64: Xs[128][64], Ws[BN][64], 16B-granule XOR swizzle.
template <int BN, bool OUT_BF16>
__global__ __launch_bounds__(256) void k_combine(const ushort* __restrict__ Xb,
                                                 const ushort* __restrict__ Gb,
                                                 const ushort* __restrict__ Wt,
                                                 const float* __restrict__ bias,
                                                 void* __restrict__ OutV, int M) {
  constexpr int WTN = BN / 2;   // wave tile N
  constexpr int FM = 4;         // 64/16 m-frags per wave
  constexpr int FN = WTN / 16;  // n-frags per wave
  __shared__ char XsB[128 * 64 * 2];
  __shared__ char WsB[BN * 64 * 2];

  const int m0 = blockIdx.x * 128;
  const int t = threadIdx.x;
  const int lane = t & 63;
  const int w = t >> 6;
  const int wm = w >> 1, wn = w & 1;

  f32x4 acc[FM][FN] = {};

  for (int kc = 0; kc < 4; kc++) {
    const ushort* Xsrc = (kc < 2) ? Xb : Gb;
    const int koff = (kc & 1) * 64;
    // stage X tile: 1024 16B granules, 4 per thread (global_load_lds)
#pragma unroll
    for (int i = 0; i < 4; i++) {
      int g = i * 256 + t;
      int row = g >> 3, kph = g & 7;
      int gm = min(m0 + row, M - 1);
      const ushort* src = Xsrc + (size_t)gm * 128 + koff + ((kph ^ (row & 7)) << 3);
      char* dst = XsB + ((i * 256 + (t & ~63)) << 4);
      GLDS(src, dst);
    }
    // stage W tile: BN*8 granules
#pragma unroll
    for (int i = 0; i < BN / 32; i++) {
      int g = i * 256 + t;
      int colr = g >> 3, kph = g & 7;
      const ushort* src = Wt + (size_t)colr * 256 + kc * 64 + ((kph ^ (colr & 7)) << 3);
      char* dst = WsB + ((i * 256 + (t & ~63)) << 4);
      GLDS(src, dst);
    }
    __syncthreads();
#pragma unroll
    for (int ks = 0; ks < 2; ks++) {
      int kslot = ks * 4 + (lane >> 4);
      short8 af[FM], bf[FN];
#pragma unroll
      for (int fm = 0; fm < FM; fm++) {
        int row = wm * 64 + fm * 16 + (lane & 15);
        af[fm] = *reinterpret_cast<const short8*>(
            XsB + row * 128 + ((kslot ^ (row & 7)) << 4));
      }
#pragma unroll
      for (int fn = 0; fn < FN; fn++) {
        int colr = wn * WTN + fn * 16 + (lane & 15);
        bf[fn] = *reinterpret_cast<const short8*>(
            WsB + colr * 128 + ((kslot ^ (colr & 7)) << 4));
      }
#pragma unroll
      for (int fm = 0; fm < FM; fm++)
#pragma unroll
        for (int fn = 0; fn < FN; fn++)
          acc[fm][fn] = __builtin_amdgcn_mfma_f32_16x16x32_bf16(
              af[fm], bf[fn], acc[fm][fn], 0, 0, 0);
    }
    __syncthreads();
  }

  // epilogue: C frag layout col=lane&15, row=(lane>>4)*4+r
#pragma unroll
  for (int fn = 0; fn < FN; fn++) {
    int colg = wn * WTN + fn * 16 + (lane & 15);
    float bb = bias[colg];
#pragma unroll
    for (int fm = 0; fm < FM; fm++) {
#pragma unroll
      for (int r = 0; r < 4; r++) {
        int rowg = m0 + wm * 64 + fm * 16 + (lane >> 4) * 4 + r;
        if (rowg >= M) continue;
        float v = fmaxf(acc[fm][fn][r] + bb, 0.f);
        if constexpr (OUT_BF16) {
          ((ushort*)OutV)[(size_t)rowg * BN + colg] = f2bf(v);
        } else {
          ((float*)OutV)[(size_t)rowg * BN + colg] = v;
        }
      }
    }
  }
}

extern "C" void kernel_launch(void* const* d_in, const int* in_sizes, int n_in,
                              void* d_out, int out_size, void* d_ws, size_t ws_size,
                              hipStream_t stream) {
  const float* h = (const float*)d_in[0];
  const int* esrc = (const int*)d_in[1];
  const int* edst = (const int*)d_in[2];
  const float* Ws1 = (const float*)d_in[3];
  const float* Wn1 = (const float*)d_in[4];
  const float* b1 = (const float*)d_in[5];
  const float* Ws2 = (const float*)d_in[6];
  const float* Wn2 = (const float*)d_in[7];
  const float* b2 = (const float*)d_in[8];
  float* out = (float*)d_out;

  const int N = in_sizes[0] / 128;  // 100000
  const int E = in_sizes[1];        // 1600000

  char* base = (char*)d_ws;
  size_t off = 0;
  auto alloc = [&](size_t bytes) {
    size_t o = off;
    off += (bytes + 255) & ~(size_t)255;
    return o;
  };
  int* deg = (int*)(base + alloc((size_t)N * 4));
  int* rs = (int*)(base + alloc((size_t)N * 4));
  int* cur = (int*)(base + alloc((size_t)N * 4));
  int* bsum = (int*)(base + alloc(512 * 4));
  int* boff = (int*)(base + alloc(512 * 4));
  int* col = (int*)(base + alloc((size_t)E * 4));
  ushort* hb = (ushort*)(base + alloc((size_t)N * 128 * 2));
  ushort* aggb = (ushort*)(base + alloc((size_t)N * 128 * 2));
  ushort* h1b = (ushort*)(base + alloc((size_t)N * 128 * 2));
  ushort* Wt1 = (ushort*)(base + alloc(128 * 256 * 2));
  ushort* Wt2 = (ushort*)(base + alloc(64 * 256 * 2));

  const int NB1 = (N + 255) / 256;  // 391 (<=512 for single-block scan)

  (void)hipMemsetAsync(deg, 0, (size_t)N * 4, stream);
  k_degree<<<(E + 255) / 256, 256, 0, stream>>>(edst, deg, E);
  k_scan_reduce<<<NB1, 256, 0, stream>>>(deg, bsum, N);
  k_scan_blocksums<<<1, 512, 0, stream>>>(bsum, boff, NB1);
  k_scan_final<<<NB1, 256, 0, stream>>>(deg, boff, rs, cur, N);
  k_fill<<<(E + 255) / 256, 256, 0, stream>>>(esrc, edst, cur, col, E);

  k_prep_w<<<(192 * 256 + 255) / 256, 256, 0, stream>>>(Ws1, Wn1, Ws2, Wn2, Wt1, Wt2);
  k_cast<<<((N * 128 / 8) + 255) / 256, 256, 0, stream>>>(h, hb, N * 128 / 8);

  // Layer 1
  k_agg_b<<<(N + 3) / 4, 256, 0, stream>>>(hb, col, rs, deg, aggb, N);
  k_combine<128, true><<<(N + 127) / 128, 256, 0, stream>>>(hb, aggb, Wt1, b1, h1b, N);

  // Layer 2
  k_agg_b<<<(N + 3) / 4, 256, 0, stream>>>(h1b, col, rs, deg, aggb, N);
  k_combine<64, false><<<(N + 127) / 128, 256, 0, stream>>>(h1b, aggb, Wt2, b2, out, N);
}

// Round 4
// 243.840 us; speedup vs baseline: 2.8999x; 1.5865x over previous
//
#include <hip/hip_runtime.h>

// GraphSAGE 2-layer (mean agg), N=100K, E=1.6M, 128->128->64, f32 in/out.
// bf16 features + MFMA GEMM. CSR-by-dst built via bucketed LDS counting sort
// (hist -> scan -> bucket-scatter -> per-bucket CSR), gather-aggregate,
// combine = [h|agg] @ [Wself;Wneigh] + b, relu.

typedef __attribute__((ext_vector_type(8))) short short8;
typedef __attribute__((ext_vector_type(4))) float f32x4;

__device__ __forceinline__ ushort f2bf(float f) {
  uint u = __float_as_uint(f);
  u += 0x7fffu + ((u >> 16) & 1u);  // round-to-nearest-even
  return (ushort)(u >> 16);
}

#define GLDS(src, dst)                                                        \
  __builtin_amdgcn_global_load_lds(                                           \
      (const __attribute__((address_space(1))) void*)(src),                   \
      (__attribute__((address_space(3))) void*)(dst), 16, 0, 0)

// ================= bucketed CSR build =================
// bucket b = dst >> 8 (256 nodes per bucket). P = ceil(N/256) <= 512.
// packed edge u32 = (src << 8) | (dst & 255).

__global__ __launch_bounds__(256) void k_bhist(const int* __restrict__ dst,
                                               int* __restrict__ bcnt, int E) {
  __shared__ int h[512];
  int t = threadIdx.x;
  for (int i = t; i < 512; i += 256) h[i] = 0;
  __syncthreads();
  int base = blockIdx.x * 8192;
  int end = min(base + 8192, E);
  for (int e = base + t; e < end; e += 256)
    atomicAdd(&h[((uint)dst[e]) >> 8], 1);
  __syncthreads();
  for (int i = t; i < 512; i += 256)
    if (h[i]) atomicAdd(&bcnt[i], h[i]);
}

__global__ __launch_bounds__(512) void k_bscan(const int* __restrict__ bcnt,
                                               int* __restrict__ bbase,
                                               int* __restrict__ bcur, int P, int E) {
  __shared__ int s[512];
  int t = threadIdx.x;
  int v = (t < P) ? bcnt[t] : 0;
  s[t] = v;
  __syncthreads();
  for (int off = 1; off < 512; off <<= 1) {
    int x = (t >= off) ? s[t - off] : 0;
    __syncthreads();
    s[t] += x;
    __syncthreads();
  }
  int ex = s[t] - v;
  if (t < P) {
    bbase[t] = ex;
    bcur[t] = ex;
  }
  if (t == P - 1) bbase[P] = E;
}

__global__ __launch_bounds__(256) void k_bscatter(const int* __restrict__ dst,
                                                  const int* __restrict__ src,
                                                  int* __restrict__ bcur,
                                                  uint* __restrict__ bed, int E, int P) {
  __shared__ int hist[512];
  __shared__ int incl[512];   // inclusive scan of hist
  __shared__ int gpos[512];
  __shared__ int cur[512];
  __shared__ uint stage[8192];
  __shared__ ushort bof[8192];
  int t = threadIdx.x;
  int base = blockIdx.x * 8192;
  int cnt = min(8192, E - base);
  for (int i = t; i < 512; i += 256) hist[i] = 0;
  __syncthreads();
  for (int i = t; i < cnt; i += 256)
    atomicAdd(&hist[((uint)dst[base + i]) >> 8], 1);
  __syncthreads();
  incl[t] = hist[t];
  incl[t + 256] = hist[t + 256];
  __syncthreads();
  for (int off = 1; off < 512; off <<= 1) {
    int i0 = t, i1 = t + 256;
    int a0 = (i0 >= off) ? incl[i0 - off] : 0;
    int a1 = (i1 >= off) ? incl[i1 - off] : 0;
    __syncthreads();
    incl[i0] += a0;
    incl[i1] += a1;
    __syncthreads();
  }
  cur[t] = incl[t] - hist[t];
  cur[t + 256] = incl[t + 256] - hist[t + 256];
  for (int i = t; i < P; i += 256)
    if (hist[i]) gpos[i] = atomicAdd(&bcur[i], hist[i]);
  __syncthreads();
  for (int i = t; i < cnt; i += 256) {
    int d = dst[base + i];
    int b = ((uint)d) >> 8;
    uint val = (((uint)src[base + i]) << 8) | (uint)(d & 255);
    int slot = atomicAdd(&cur[b], 1);
    stage[slot] = val;
    bof[slot] = (ushort)b;
  }
  __syncthreads();
  for (int i = t; i < cnt; i += 256) {
    int b = bof[i];
    int ex = incl[b] - hist[b];
    bed[gpos[b] + (i - ex)] = stage[i];
  }
}

// one block per bucket: build deg/rs for its 256 nodes, write col sorted.
__global__ __launch_bounds__(256) void k_bcsr(const uint* __restrict__ bed,
                                              const int* __restrict__ bbase,
                                              int* __restrict__ deg,
                                              int* __restrict__ rs,
                                              int* __restrict__ col, int N) {
  __shared__ int dcnt[256];
  __shared__ int sofs[256];
  int b = blockIdx.x, t = threadIdx.x;
  int e0 = bbase[b], e1 = bbase[b + 1];
  dcnt[t] = 0;
  __syncthreads();
  for (int e = e0 + t; e < e1; e += 256) atomicAdd(&dcnt[bed[e] & 255u], 1);
  __syncthreads();
  int v0 = dcnt[t];
  sofs[t] = v0;
  __syncthreads();
  for (int off = 1; off < 256; off <<= 1) {
    int x = (t >= off) ? sofs[t - off] : 0;
    __syncthreads();
    sofs[t] += x;
    __syncthreads();
  }
  int ex = sofs[t] - v0;
  int node = (b << 8) + t;
  if (node < N) {
    deg[node] = v0;
    rs[node] = e0 + ex;
  }
  __syncthreads();
  dcnt[t] = e0 + ex;  // reuse as global cursors
  __syncthreads();
  for (int e = e0 + t; e < e1; e += 256) {
    uint v = bed[e];
    int pos = atomicAdd(&dcnt[v & 255u], 1);
    col[pos] = (int)(v >> 8);
  }
}

// ---------------- prep: f32 -> bf16 cast of h ----------------
__global__ __launch_bounds__(256) void k_cast(const float* __restrict__ in,
                                              ushort* __restrict__ out, int n8) {
  int i = blockIdx.x * 256 + threadIdx.x;
  if (i >= n8) return;
  const float4* p = reinterpret_cast<const float4*>(in) + i * 2;
  float4 a = p[0], b = p[1];
  ushort u[8];
  u[0] = f2bf(a.x); u[1] = f2bf(a.y); u[2] = f2bf(a.z); u[3] = f2bf(a.w);
  u[4] = f2bf(b.x); u[5] = f2bf(b.y); u[6] = f2bf(b.z); u[7] = f2bf(b.w);
  *reinterpret_cast<ulonglong2*>(out + (size_t)i * 8) =
      *reinterpret_cast<ulonglong2*>(u);
}

// ---------------- prep: transpose+concat weights to bf16 Wt[n][256] ----------
__global__ __launch_bounds__(256) void k_prep_w(const float* __restrict__ Ws1,
                                                const float* __restrict__ Wn1,
                                                const float* __restrict__ Ws2,
                                                const float* __restrict__ Wn2,
                                                ushort* __restrict__ Wt1,
                                                ushort* __restrict__ Wt2) {
  int idx = blockIdx.x * 256 + threadIdx.x;
  if (idx < 128 * 256) {
    int n = idx >> 8, k = idx & 255;
    float v = (k < 128) ? Ws1[(size_t)k * 128 + n] : Wn1[(size_t)(k - 128) * 128 + n];
    Wt1[idx] = f2bf(v);
  } else if (idx < 128 * 256 + 64 * 256) {
    int j = idx - 128 * 256;
    int n = j >> 8, k = j & 255;
    float v = (k < 128) ? Ws2[(size_t)k * 64 + n] : Wn2[(size_t)(k - 128) * 64 + n];
    Wt2[j] = f2bf(v);
  }
}

// ---------------- mean-aggregate (bf16 rows, 256B each) ----------------
__global__ __launch_bounds__(256) void k_agg_b(const ushort* __restrict__ Xb,
                                               const int* __restrict__ col,
                                               const int* __restrict__ rs,
                                               const int* __restrict__ deg,
                                               ushort* __restrict__ outb, int n) {
  int node = blockIdx.x * 4 + (threadIdx.x >> 6);
  if (node >= n) return;
  int lane = threadIdx.x & 63;
  int r0 = rs[node];
  int d = deg[node];
  float ax0 = 0.f, ay0 = 0.f, ax1 = 0.f, ay1 = 0.f;
  float ax2 = 0.f, ay2 = 0.f, ax3 = 0.f, ay3 = 0.f;
  int j = 0;
  while (j < d) {
    int cnt = min(d - j, 64);
    int myc = (lane < cnt) ? col[r0 + j + lane] : 0;
    int jj = 0;
    for (; jj + 4 <= cnt; jj += 4) {
      int c0 = __shfl(myc, jj, 64);
      int c1 = __shfl(myc, jj + 1, 64);
      int c2 = __shfl(myc, jj + 2, 64);
      int c3 = __shfl(myc, jj + 3, 64);
      uint v0 = *reinterpret_cast<const uint*>(&Xb[(size_t)c0 * 128 + lane * 2]);
      uint v1 = *reinterpret_cast<const uint*>(&Xb[(size_t)c1 * 128 + lane * 2]);
      uint v2 = *reinterpret_cast<const uint*>(&Xb[(size_t)c2 * 128 + lane * 2]);
      uint v3 = *reinterpret_cast<const uint*>(&Xb[(size_t)c3 * 128 + lane * 2]);
      ax0 += __uint_as_float(v0 << 16); ay0 += __uint_as_float(v0 & 0xffff0000u);
      ax1 += __uint_as_float(v1 << 16); ay1 += __uint_as_float(v1 & 0xffff0000u);
      ax2 += __uint_as_float(v2 << 16); ay2 += __uint_as_float(v2 & 0xffff0000u);
      ax3 += __uint_as_float(v3 << 16); ay3 += __uint_as_float(v3 & 0xffff0000u);
    }
    for (; jj < cnt; jj++) {
      int c0 = __shfl(myc, jj, 64);
      uint v0 = *reinterpret_cast<const uint*>(&Xb[(size_t)c0 * 128 + lane * 2]);
      ax0 += __uint_as_float(v0 << 16); ay0 += __uint_as_float(v0 & 0xffff0000u);
    }
    j += cnt;
  }
  float rinv = 1.0f / fmaxf((float)d, 1.0f);
  float sx = (ax0 + ax1 + ax2 + ax3) * rinv;
  float sy = (ay0 + ay1 + ay2 + ay3) * rinv;
  ushort2 o;
  o.x = f2bf(sx);
  o.y = f2bf(sy);
  *reinterpret_cast<ushort2*>(&outb[(size_t)node * 128 + lane * 2]) = o;
}

// ---------------- combine: relu( [Xb|Gb] @ Wt^T + bias ) via MFMA ----------
template <int BN, bool OUT_BF16>
__global__ __launch_bounds__(256) void k_combine(const ushort* __restrict__ Xb,
                                                 const ushort* __restrict__ Gb,
                                                 const ushort* __restrict__ Wt,
                                                 const float* __restrict__ bias,
                                                 void* __restrict__ OutV, int M) {
  constexpr int WTN = BN / 2;
  constexpr int FM = 4;
  constexpr int FN = WTN / 16;
  __shared__ char XsB[128 * 64 * 2];
  __shared__ char WsB[BN * 64 * 2];

  const int m0 = blockIdx.x * 128;
  const int t = threadIdx.x;
  const int lane = t & 63;
  const int w = t >> 6;
  const int wm = w >> 1, wn = w & 1;

  f32x4 acc[FM][FN] = {};

  for (int kc = 0; kc < 4; kc++) {
    const ushort* Xsrc = (kc < 2) ? Xb : Gb;
    const int koff = (kc & 1) * 64;
#pragma unroll
    for (int i = 0; i < 4; i++) {
      int g = i * 256 + t;
      int row = g >> 3, kph = g & 7;
      int gm = min(m0 + row, M - 1);
      const ushort* src = Xsrc + (size_t)gm * 128 + koff + ((kph ^ (row & 7)) << 3);
      char* dst = XsB + ((i * 256 + (t & ~63)) << 4);
      GLDS(src, dst);
    }
#pragma unroll
    for (int i = 0; i < BN / 32; i++) {
      int g = i * 256 + t;
      int colr = g >> 3, kph = g & 7;
      const ushort* src = Wt + (size_t)colr * 256 + kc * 64 + ((kph ^ (colr & 7)) << 3);
      char* dst = WsB + ((i * 256 + (t & ~63)) << 4);
      GLDS(src, dst);
    }
    __syncthreads();
#pragma unroll
    for (int ks = 0; ks < 2; ks++) {
      int kslot = ks * 4 + (lane >> 4);
      short8 af[FM], bf[FN];
#pragma unroll
      for (int fm = 0; fm < FM; fm++) {
        int row = wm * 64 + fm * 16 + (lane & 15);
        af[fm] = *reinterpret_cast<const short8*>(
            XsB + row * 128 + ((kslot ^ (row & 7)) << 4));
      }
#pragma unroll
      for (int fn = 0; fn < FN; fn++) {
        int colr = wn * WTN + fn * 16 + (lane & 15);
        bf[fn] = *reinterpret_cast<const short8*>(
            WsB + colr * 128 + ((kslot ^ (colr & 7)) << 4));
      }
#pragma unroll
      for (int fm = 0; fm < FM; fm++)
#pragma unroll
        for (int fn = 0; fn < FN; fn++)
          acc[fm][fn] = __builtin_amdgcn_mfma_f32_16x16x32_bf16(
              af[fm], bf[fn], acc[fm][fn], 0, 0, 0);
    }
    __syncthreads();
  }

#pragma unroll
  for (int fn = 0; fn < FN; fn++) {
    int colg = wn * WTN + fn * 16 + (lane & 15);
    float bb = bias[colg];
#pragma unroll
    for (int fm = 0; fm < FM; fm++) {
#pragma unroll
      for (int r = 0; r < 4; r++) {
        int rowg = m0 + wm * 64 + fm * 16 + (lane >> 4) * 4 + r;
        if (rowg >= M) continue;
        float v = fmaxf(acc[fm][fn][r] + bb, 0.f);
        if constexpr (OUT_BF16) {
          ((ushort*)OutV)[(size_t)rowg * BN + colg] = f2bf(v);
        } else {
          ((float*)OutV)[(size_t)rowg * BN + colg] = v;
        }
      }
    }
  }
}

extern "C" void kernel_launch(void* const* d_in, const int* in_sizes, int n_in,
                              void* d_out, int out_size, void* d_ws, size_t ws_size,
                              hipStream_t stream) {
  const float* h = (const float*)d_in[0];
  const int* esrc = (const int*)d_in[1];
  const int* edst = (const int*)d_in[2];
  const float* Ws1 = (const float*)d_in[3];
  const float* Wn1 = (const float*)d_in[4];
  const float* b1 = (const float*)d_in[5];
  const float* Ws2 = (const float*)d_in[6];
  const float* Wn2 = (const float*)d_in[7];
  const float* b2 = (const float*)d_in[8];
  float* out = (float*)d_out;

  const int N = in_sizes[0] / 128;  // 100000
  const int E = in_sizes[1];        // 1600000
  const int P = (N + 255) >> 8;     // 391 buckets (<=512)

  char* base = (char*)d_ws;
  size_t off = 0;
  auto alloc = [&](size_t bytes) {
    size_t o = off;
    off += (bytes + 255) & ~(size_t)255;
    return o;
  };
  int* deg = (int*)(base + alloc((size_t)N * 4));
  int* rs = (int*)(base + alloc((size_t)N * 4));
  int* bcnt = (int*)(base + alloc(513 * 4));
  int* bbase = (int*)(base + alloc(513 * 4));
  int* bcur = (int*)(base + alloc(513 * 4));
  uint* bed = (uint*)(base + alloc((size_t)E * 4));
  int* col = (int*)(base + alloc((size_t)E * 4));
  ushort* hb = (ushort*)(base + alloc((size_t)N * 128 * 2));
  ushort* aggb = (ushort*)(base + alloc((size_t)N * 128 * 2));
  ushort* h1b = (ushort*)(base + alloc((size_t)N * 128 * 2));
  ushort* Wt1 = (ushort*)(base + alloc(128 * 256 * 2));
  ushort* Wt2 = (ushort*)(base + alloc(64 * 256 * 2));

  const int NCH = (E + 8191) / 8192;  // edge chunks

  (void)hipMemsetAsync(bcnt, 0, 513 * 4, stream);
  k_bhist<<<NCH, 256, 0, stream>>>(edst, bcnt, E);
  k_bscan<<<1, 512, 0, stream>>>(bcnt, bbase, bcur, P, E);
  k_bscatter<<<NCH, 256, 0, stream>>>(edst, esrc, bcur, bed, E, P);
  k_bcsr<<<P, 256, 0, stream>>>(bed, bbase, deg, rs, col, N);

  k_prep_w<<<(192 * 256 + 255) / 256, 256, 0, stream>>>(Ws1, Wn1, Ws2, Wn2, Wt1, Wt2);
  k_cast<<<((N * 128 / 8) + 255) / 256, 256, 0, stream>>>(h, hb, N * 128 / 8);

  // Layer 1
  k_agg_b<<<(N + 3) / 4, 256, 0, stream>>>(hb, col, rs, deg, aggb, N);
  k_combine<128, true><<<(N + 127) / 128, 256, 0, stream>>>(hb, aggb, Wt1, b1, h1b, N);

  // Layer 2
  k_agg_b<<<(N + 3) / 4, 256, 0, stream>>>(h1b, col, rs, deg, aggb, N);
  k_combine<64, false><<<(N + 127) / 128, 256, 0, stream>>>(h1b, aggb, Wt2, b2, out, N);
}

// Round 6
// 234.635 us; speedup vs baseline: 3.0137x; 1.0392x over previous
//
#include <hip/hip_runtime.h>

// GraphSAGE 2-layer (mean agg), N=100K, E=1.6M, 128->128->64, f32 in/out.
// bf16 features + MFMA GEMM. CSR-by-dst via bucketed LDS counting sort.
// Layer1: agg(h) -> [h|agg]@Wt1 (K=256). Layer2 (mean is linear):
// one K=128 GEMM -> {p2=h1@Wn2 (bf16), s2=h1@Ws2+b2 (f32)}, then
// out = relu(s2 + mean-gather(p2)) with 64-wide rows (half gather traffic).
// NOTE: remainder shfl must be executed wave-uniformly (ds_bpermute returns 0
// for inactive source lanes) — guard only the load, never the shfl.

typedef __attribute__((ext_vector_type(8))) short short8;
typedef __attribute__((ext_vector_type(4))) float f32x4;

__device__ __forceinline__ ushort f2bf(float f) {
  uint u = __float_as_uint(f);
  u += 0x7fffu + ((u >> 16) & 1u);  // round-to-nearest-even
  return (ushort)(u >> 16);
}
__device__ __forceinline__ float bl(uint u) { return __uint_as_float(u << 16); }
__device__ __forceinline__ float bh(uint u) { return __uint_as_float(u & 0xffff0000u); }

#define GLDS(src, dst)                                                        \
  __builtin_amdgcn_global_load_lds(                                           \
      (const __attribute__((address_space(1))) void*)(src),                   \
      (__attribute__((address_space(3))) void*)(dst), 16, 0, 0)

// ================= bucketed CSR build =================
__global__ __launch_bounds__(256) void k_bhist(const int* __restrict__ dst,
                                               int* __restrict__ bcnt, int E) {
  __shared__ int h[512];
  int t = threadIdx.x;
  for (int i = t; i < 512; i += 256) h[i] = 0;
  __syncthreads();
  int base = blockIdx.x * 8192;
  int end = min(base + 8192, E);
  for (int e = base + t; e < end; e += 256)
    atomicAdd(&h[((uint)dst[e]) >> 8], 1);
  __syncthreads();
  for (int i = t; i < 512; i += 256)
    if (h[i]) atomicAdd(&bcnt[i], h[i]);
}

__global__ __launch_bounds__(512) void k_bscan(const int* __restrict__ bcnt,
                                               int* __restrict__ bbase,
                                               int* __restrict__ bcur, int P, int E) {
  __shared__ int s[512];
  int t = threadIdx.x;
  int v = (t < P) ? bcnt[t] : 0;
  s[t] = v;
  __syncthreads();
  for (int off = 1; off < 512; off <<= 1) {
    int x = (t >= off) ? s[t - off] : 0;
    __syncthreads();
    s[t] += x;
    __syncthreads();
  }
  int ex = s[t] - v;
  if (t < P) {
    bbase[t] = ex;
    bcur[t] = ex;
  }
  if (t == P - 1) bbase[P] = E;
}

__global__ __launch_bounds__(256) void k_bscatter(const int* __restrict__ dst,
                                                  const int* __restrict__ src,
                                                  int* __restrict__ bcur,
                                                  uint* __restrict__ bed, int E, int P) {
  __shared__ int hist[512];
  __shared__ int incl[512];
  __shared__ int gpos[512];
  __shared__ int cur[512];
  __shared__ uint stage[8192];
  __shared__ ushort bof[8192];
  int t = threadIdx.x;
  int base = blockIdx.x * 8192;
  int cnt = min(8192, E - base);
  for (int i = t; i < 512; i += 256) hist[i] = 0;
  __syncthreads();
  for (int i = t; i < cnt; i += 256)
    atomicAdd(&hist[((uint)dst[base + i]) >> 8], 1);
  __syncthreads();
  incl[t] = hist[t];
  incl[t + 256] = hist[t + 256];
  __syncthreads();
  for (int off = 1; off < 512; off <<= 1) {
    int i0 = t, i1 = t + 256;
    int a0 = (i0 >= off) ? incl[i0 - off] : 0;
    int a1 = (i1 >= off) ? incl[i1 - off] : 0;
    __syncthreads();
    incl[i0] += a0;
    incl[i1] += a1;
    __syncthreads();
  }
  cur[t] = incl[t] - hist[t];
  cur[t + 256] = incl[t + 256] - hist[t + 256];
  for (int i = t; i < P; i += 256)
    if (hist[i]) gpos[i] = atomicAdd(&bcur[i], hist[i]);
  __syncthreads();
  for (int i = t; i < cnt; i += 256) {
    int d = dst[base + i];
    int b = ((uint)d) >> 8;
    uint val = (((uint)src[base + i]) << 8) | (uint)(d & 255);
    int slot = atomicAdd(&cur[b], 1);
    stage[slot] = val;
    bof[slot] = (ushort)b;
  }
  __syncthreads();
  for (int i = t; i < cnt; i += 256) {
    int b = bof[i];
    int ex = incl[b] - hist[b];
    bed[gpos[b] + (i - ex)] = stage[i];
  }
}

__global__ __launch_bounds__(256) void k_bcsr(const uint* __restrict__ bed,
                                              const int* __restrict__ bbase,
                                              int* __restrict__ deg,
                                              int* __restrict__ rs,
                                              int* __restrict__ col, int N) {
  __shared__ int dcnt[256];
  __shared__ int sofs[256];
  int b = blockIdx.x, t = threadIdx.x;
  int e0 = bbase[b], e1 = bbase[b + 1];
  dcnt[t] = 0;
  __syncthreads();
  for (int e = e0 + t; e < e1; e += 256) atomicAdd(&dcnt[bed[e] & 255u], 1);
  __syncthreads();
  int v0 = dcnt[t];
  sofs[t] = v0;
  __syncthreads();
  for (int off = 1; off < 256; off <<= 1) {
    int x = (t >= off) ? sofs[t - off] : 0;
    __syncthreads();
    sofs[t] += x;
    __syncthreads();
  }
  int ex = sofs[t] - v0;
  int node = (b << 8) + t;
  if (node < N) {
    deg[node] = v0;
    rs[node] = e0 + ex;
  }
  __syncthreads();
  dcnt[t] = e0 + ex;
  __syncthreads();
  for (int e = e0 + t; e < e1; e += 256) {
    uint v = bed[e];
    int pos = atomicAdd(&dcnt[v & 255u], 1);
    col[pos] = (int)(v >> 8);
  }
}

// ---------------- prep: f32 -> bf16 cast of h ----------------
__global__ __launch_bounds__(256) void k_cast(const float* __restrict__ in,
                                              ushort* __restrict__ out, int n8) {
  int i = blockIdx.x * 256 + threadIdx.x;
  if (i >= n8) return;
  const float4* p = reinterpret_cast<const float4*>(in) + i * 2;
  float4 a = p[0], b = p[1];
  ushort u[8];
  u[0] = f2bf(a.x); u[1] = f2bf(a.y); u[2] = f2bf(a.z); u[3] = f2bf(a.w);
  u[4] = f2bf(b.x); u[5] = f2bf(b.y); u[6] = f2bf(b.z); u[7] = f2bf(b.w);
  *reinterpret_cast<ulonglong2*>(out + (size_t)i * 8) =
      *reinterpret_cast<ulonglong2*>(u);
}

// prep weights: Wt1[n][k0..255] = [Ws1;Wn1]^T ; Wt2cat[n][k0..127]:
// n<64 -> Wn2[k][n] (p2 half), n>=64 -> Ws2[k][n-64] (s2 half).
__global__ __launch_bounds__(256) void k_prep_w(const float* __restrict__ Ws1,
                                                const float* __restrict__ Wn1,
                                                const float* __restrict__ Ws2,
                                                const float* __restrict__ Wn2,
                                                ushort* __restrict__ Wt1,
                                                ushort* __restrict__ Wt2cat) {
  int idx = blockIdx.x * 256 + threadIdx.x;
  if (idx < 128 * 256) {
    int n = idx >> 8, k = idx & 255;
    float v = (k < 128) ? Ws1[(size_t)k * 128 + n] : Wn1[(size_t)(k - 128) * 128 + n];
    Wt1[idx] = f2bf(v);
  } else if (idx < 128 * 256 + 128 * 128) {
    int j = idx - 128 * 256;
    int n = j >> 7, k = j & 127;
    float v = (n < 64) ? Wn2[(size_t)k * 64 + n] : Ws2[(size_t)k * 64 + (n - 64)];
    Wt2cat[j] = f2bf(v);
  }
}

// ---------------- layer-1 aggregate: 128-feat bf16 rows (256B) ----------------
// wave per node; lane: row-group = lane>>4 (4 rows/iter), slot = lane&15 (16B).
__global__ __launch_bounds__(256) void k_agg1(const ushort* __restrict__ Xb,
                                              const int* __restrict__ col,
                                              const int* __restrict__ rs,
                                              const int* __restrict__ deg,
                                              ushort* __restrict__ outb, int n) {
  int node = blockIdx.x * 4 + (threadIdx.x >> 6);
  if (node >= n) return;
  int lane = threadIdx.x & 63;
  int grp = lane >> 4, sl = lane & 15;
  int r0 = rs[node], d = deg[node];
  float a[8] = {};
  int j = 0;
  while (j < d) {
    int cnt = min(d - j, 64);
    int myc = (lane < cnt) ? col[r0 + j + lane] : 0;
    int jj = 0;
    for (; jj + 4 <= cnt; jj += 4) {
      int c = __shfl(myc, jj + grp, 64);
      uint4 v = *reinterpret_cast<const uint4*>(Xb + (size_t)c * 128 + sl * 8);
      a[0] += bl(v.x); a[1] += bh(v.x); a[2] += bl(v.y); a[3] += bh(v.y);
      a[4] += bl(v.z); a[5] += bh(v.z); a[6] += bl(v.w); a[7] += bh(v.w);
    }
    int rem = cnt - jj;
    if (rem > 0) {                          // wave-uniform branch
      int c = __shfl(myc, jj + grp, 64);    // all 64 lanes execute the shfl
      if (grp < rem) {                      // only the load is guarded
        uint4 v = *reinterpret_cast<const uint4*>(Xb + (size_t)c * 128 + sl * 8);
        a[0] += bl(v.x); a[1] += bh(v.x); a[2] += bl(v.y); a[3] += bh(v.y);
        a[4] += bl(v.z); a[5] += bh(v.z); a[6] += bl(v.w); a[7] += bh(v.w);
      }
    }
    j += cnt;
  }
#pragma unroll
  for (int k = 0; k < 8; k++) {
    a[k] += __shfl_xor(a[k], 16, 64);
    a[k] += __shfl_xor(a[k], 32, 64);
  }
  if (grp == 0) {
    float rinv = 1.0f / fmaxf((float)d, 1.0f);
    ushort o[8];
#pragma unroll
    for (int k = 0; k < 8; k++) o[k] = f2bf(a[k] * rinv);
    *reinterpret_cast<ulonglong2*>(outb + (size_t)node * 128 + sl * 8) =
        *reinterpret_cast<ulonglong2*>(o);
  }
}

// ---------------- layer-2 fused gather+add: 64-feat bf16 rows (128B) ----------
// out = relu(s2 + mean-gather(p2)); row-group = lane>>3 (8 rows/iter), slot = lane&7.
__global__ __launch_bounds__(256) void k_agg_out(const ushort* __restrict__ Pb,
                                                 const float* __restrict__ S,
                                                 const int* __restrict__ col,
                                                 const int* __restrict__ rs,
                                                 const int* __restrict__ deg,
                                                 float* __restrict__ out, int n) {
  int node = blockIdx.x * 4 + (threadIdx.x >> 6);
  if (node >= n) return;
  int lane = threadIdx.x & 63;
  int grp = lane >> 3, sl = lane & 7;
  int r0 = rs[node], d = deg[node];
  float a[8] = {};
  int j = 0;
  while (j < d) {
    int cnt = min(d - j, 64);
    int myc = (lane < cnt) ? col[r0 + j + lane] : 0;
    int jj = 0;
    for (; jj + 8 <= cnt; jj += 8) {
      int c = __shfl(myc, jj + grp, 64);
      uint4 v = *reinterpret_cast<const uint4*>(Pb + (size_t)c * 64 + sl * 8);
      a[0] += bl(v.x); a[1] += bh(v.x); a[2] += bl(v.y); a[3] += bh(v.y);
      a[4] += bl(v.z); a[5] += bh(v.z); a[6] += bl(v.w); a[7] += bh(v.w);
    }
    int rem = cnt - jj;
    if (rem > 0) {                          // wave-uniform branch
      int c = __shfl(myc, jj + grp, 64);    // all 64 lanes execute the shfl
      if (grp < rem) {
        uint4 v = *reinterpret_cast<const uint4*>(Pb + (size_t)c * 64 + sl * 8);
        a[0] += bl(v.x); a[1] += bh(v.x); a[2] += bl(v.y); a[3] += bh(v.y);
        a[4] += bl(v.z); a[5] += bh(v.z); a[6] += bl(v.w); a[7] += bh(v.w);
      }
    }
    j += cnt;
  }
#pragma unroll
  for (int k = 0; k < 8; k++) {
    a[k] += __shfl_xor(a[k], 8, 64);
    a[k] += __shfl_xor(a[k], 16, 64);
    a[k] += __shfl_xor(a[k], 32, 64);
  }
  if (grp == 0) {
    float rinv = 1.0f / fmaxf((float)d, 1.0f);
    const float4* sp = reinterpret_cast<const float4*>(S + (size_t)node * 64 + sl * 8);
    float4 s0 = sp[0], s1 = sp[1];
    float4 o0, o1;
    o0.x = fmaxf(a[0] * rinv + s0.x, 0.f);
    o0.y = fmaxf(a[1] * rinv + s0.y, 0.f);
    o0.z = fmaxf(a[2] * rinv + s0.z, 0.f);
    o0.w = fmaxf(a[3] * rinv + s0.w, 0.f);
    o1.x = fmaxf(a[4] * rinv + s1.x, 0.f);
    o1.y = fmaxf(a[5] * rinv + s1.y, 0.f);
    o1.z = fmaxf(a[6] * rinv + s1.z, 0.f);
    o1.w = fmaxf(a[7] * rinv + s1.w, 0.f);
    float4* op = reinterpret_cast<float4*>(out + (size_t)node * 64 + sl * 8);
    op[0] = o0;
    op[1] = o1;
  }
}

// ---------------- MFMA combine ----------------
// MODE 0: OutA = relu(X|G @ Wt + bias) bf16, BN cols.
// MODE 1: cols<64 -> OutA=f2bf(acc) raw (p2); cols>=64 -> OutB=acc+bias[c-64] f32 (s2).
template <int BN, int KCH, int MODE>
__global__ __launch_bounds__(256) void k_combine(const ushort* __restrict__ Xb,
                                                 const ushort* __restrict__ Gb,
                                                 const ushort* __restrict__ Wt,
                                                 const float* __restrict__ bias,
                                                 void* __restrict__ OutA,
                                                 void* __restrict__ OutB, int M) {
  constexpr int WTN = BN / 2;
  constexpr int FM = 4;
  constexpr int FN = WTN / 16;
  __shared__ char XsB[128 * 64 * 2];
  __shared__ char WsB[BN * 64 * 2];

  const int m0 = blockIdx.x * 128;
  const int t = threadIdx.x;
  const int lane = t & 63;
  const int w = t >> 6;
  const int wm = w >> 1, wn = w & 1;

  f32x4 acc[FM][FN] = {};

  for (int kc = 0; kc < KCH; kc++) {
    const ushort* Xsrc = (kc < 2) ? Xb : Gb;
    const int koff = (kc & 1) * 64;
#pragma unroll
    for (int i = 0; i < 4; i++) {
      int g = i * 256 + t;
      int row = g >> 3, kph = g & 7;
      int gm = min(m0 + row, M - 1);
      const ushort* src = Xsrc + (size_t)gm * 128 + koff + ((kph ^ (row & 7)) << 3);
      char* dst = XsB + ((i * 256 + (t & ~63)) << 4);
      GLDS(src, dst);
    }
#pragma unroll
    for (int i = 0; i < BN / 32; i++) {
      int g = i * 256 + t;
      int colr = g >> 3, kph = g & 7;
      const ushort* src =
          Wt + (size_t)colr * (KCH * 64) + kc * 64 + ((kph ^ (colr & 7)) << 3);
      char* dst = WsB + ((i * 256 + (t & ~63)) << 4);
      GLDS(src, dst);
    }
    __syncthreads();
#pragma unroll
    for (int ks = 0; ks < 2; ks++) {
      int kslot = ks * 4 + (lane >> 4);
      short8 af[FM], bf[FN];
#pragma unroll
      for (int fm = 0; fm < FM; fm++) {
        int row = wm * 64 + fm * 16 + (lane & 15);
        af[fm] = *reinterpret_cast<const short8*>(
            XsB + row * 128 + ((kslot ^ (row & 7)) << 4));
      }
#pragma unroll
      for (int fn = 0; fn < FN; fn++) {
        int colr = wn * WTN + fn * 16 + (lane & 15);
        bf[fn] = *reinterpret_cast<const short8*>(
            WsB + colr * 128 + ((kslot ^ (colr & 7)) << 4));
      }
#pragma unroll
      for (int fm = 0; fm < FM; fm++)
#pragma unroll
        for (int fn = 0; fn < FN; fn++)
          acc[fm][fn] = __builtin_amdgcn_mfma_f32_16x16x32_bf16(
              af[fm], bf[fn], acc[fm][fn], 0, 0, 0);
    }
    __syncthreads();
  }

#pragma unroll
  for (int fn = 0; fn < FN; fn++) {
    int colg = wn * WTN + fn * 16 + (lane & 15);
    float bb;
    if constexpr (MODE == 0) bb = bias[colg];
    else bb = (colg >= 64) ? bias[colg - 64] : 0.f;
#pragma unroll
    for (int fm = 0; fm < FM; fm++) {
#pragma unroll
      for (int r = 0; r < 4; r++) {
        int rowg = m0 + wm * 64 + fm * 16 + (lane >> 4) * 4 + r;
        if (rowg >= M) continue;
        if constexpr (MODE == 0) {
          float v = fmaxf(acc[fm][fn][r] + bb, 0.f);
          ((ushort*)OutA)[(size_t)rowg * BN + colg] = f2bf(v);
        } else {
          if (colg < 64) {
            ((ushort*)OutA)[(size_t)rowg * 64 + colg] = f2bf(acc[fm][fn][r]);
          } else {
            ((float*)OutB)[(size_t)rowg * 64 + (colg - 64)] = acc[fm][fn][r] + bb;
          }
        }
      }
    }
  }
}

extern "C" void kernel_launch(void* const* d_in, const int* in_sizes, int n_in,
                              void* d_out, int out_size, void* d_ws, size_t ws_size,
                              hipStream_t stream) {
  const float* h = (const float*)d_in[0];
  const int* esrc = (const int*)d_in[1];
  const int* edst = (const int*)d_in[2];
  const float* Ws1 = (const float*)d_in[3];
  const float* Wn1 = (const float*)d_in[4];
  const float* b1 = (const float*)d_in[5];
  const float* Ws2 = (const float*)d_in[6];
  const float* Wn2 = (const float*)d_in[7];
  const float* b2 = (const float*)d_in[8];
  float* out = (float*)d_out;

  const int N = in_sizes[0] / 128;  // 100000
  const int E = in_sizes[1];        // 1600000
  const int P = (N + 255) >> 8;     // 391 buckets (<=512)

  char* base = (char*)d_ws;
  size_t off = 0;
  auto alloc = [&](size_t bytes) {
    size_t o = off;
    off += (bytes + 255) & ~(size_t)255;
    return o;
  };
  int* deg = (int*)(base + alloc((size_t)N * 4));
  int* rs = (int*)(base + alloc((size_t)N * 4));
  int* bcnt = (int*)(base + alloc(513 * 4));
  int* bbase = (int*)(base + alloc(513 * 4));
  int* bcur = (int*)(base + alloc(513 * 4));
  uint* bed = (uint*)(base + alloc((size_t)E * 4));
  int* col = (int*)(base + alloc((size_t)E * 4));
  ushort* hb = (ushort*)(base + alloc((size_t)N * 128 * 2));
  ushort* aggb = (ushort*)(base + alloc((size_t)N * 128 * 2));
  ushort* h1b = (ushort*)(base + alloc((size_t)N * 128 * 2));
  ushort* Wt1 = (ushort*)(base + alloc(128 * 256 * 2));
  ushort* Wt2cat = (ushort*)(base + alloc(128 * 128 * 2));
  // overlays (regions dead by the time they're written):
  ushort* p2b = hb;          // layer-2 p2 [N][64] bf16 (hb last read by combine1)
  float* s2f = (float*)aggb; // layer-2 s2 [N][64] f32  (aggb last read by combine1)

  const int NCH = (E + 8191) / 8192;

  (void)hipMemsetAsync(bcnt, 0, 513 * 4, stream);
  k_bhist<<<NCH, 256, 0, stream>>>(edst, bcnt, E);
  k_bscan<<<1, 512, 0, stream>>>(bcnt, bbase, bcur, P, E);
  k_bscatter<<<NCH, 256, 0, stream>>>(edst, esrc, bcur, bed, E, P);
  k_bcsr<<<P, 256, 0, stream>>>(bed, bbase, deg, rs, col, N);

  k_prep_w<<<((128 * 256 + 128 * 128) + 255) / 256, 256, 0, stream>>>(
      Ws1, Wn1, Ws2, Wn2, Wt1, Wt2cat);
  k_cast<<<((N * 128 / 8) + 255) / 256, 256, 0, stream>>>(h, hb, N * 128 / 8);

  // Layer 1
  k_agg1<<<(N + 3) / 4, 256, 0, stream>>>(hb, col, rs, deg, aggb, N);
  k_combine<128, 4, 0><<<(N + 127) / 128, 256, 0, stream>>>(hb, aggb, Wt1, b1,
                                                            h1b, nullptr, N);
  // Layer 2: one K=128 GEMM -> p2 (bf16) + s2 (f32), then fused gather+add+relu
  k_combine<128, 2, 1><<<(N + 127) / 128, 256, 0, stream>>>(h1b, nullptr, Wt2cat,
                                                            b2, p2b, s2f, N);
  k_agg_out<<<(N + 3) / 4, 256, 0, stream>>>(p2b, s2f, col, rs, deg, out, N);
}